// Round 1
// baseline (2999.416 us; speedup 1.0000x reference)
//
#include <hip/hip_runtime.h>
#include <cstdint>

#define IPB 10

__device__ __forceinline__ float dot64r(const float (&xr)[64], const float* __restrict__ w){
  float a0=0.f,a1=0.f,a2=0.f,a3=0.f;
  #pragma unroll
  for (int d=0; d<64; d+=4){
    a0 = fmaf(xr[d  ], w[d  ], a0);
    a1 = fmaf(xr[d+1], w[d+1], a1);
    a2 = fmaf(xr[d+2], w[d+2], a2);
    a3 = fmaf(xr[d+3], w[d+3], a3);
  }
  return (a0+a1)+(a2+a3);
}

__device__ __forceinline__ void ln64(float (&v)[64], const float* __restrict__ g, const float* __restrict__ b){
  float s0=0.f,s1=0.f,s2=0.f,s3=0.f;
  #pragma unroll
  for (int d=0; d<64; d+=4){ s0+=v[d]; s1+=v[d+1]; s2+=v[d+2]; s3+=v[d+3]; }
  float m = ((s0+s1)+(s2+s3)) * 0.015625f;
  s0=s1=s2=s3=0.f;
  #pragma unroll
  for (int d=0; d<64; d+=4){
    float t0=v[d]-m, t1=v[d+1]-m, t2=v[d+2]-m, t3=v[d+3]-m;
    s0=fmaf(t0,t0,s0); s1=fmaf(t1,t1,s1); s2=fmaf(t2,t2,s2); s3=fmaf(t3,t3,s3);
  }
  float var = ((s0+s1)+(s2+s3)) * 0.015625f;
  float inv = 1.0f / sqrtf(var + 1e-5f);
  #pragma unroll
  for (int d=0; d<64; d++) v[d] = fmaf((v[d]-m)*inv, g[d], b[d]);
}

// ---------------- prep: pattern inverse norms ----------------
__global__ void kPinv(const float* __restrict__ pm, float* __restrict__ pinv){
  __shared__ float red[256];
  int p = blockIdx.x, tid = threadIdx.x;
  float ss = 0.f;
  for (int k = tid; k < 1600; k += 256){ float v = pm[(size_t)p*1600 + k]; ss = fmaf(v,v,ss); }
  red[tid] = ss; __syncthreads();
  for (int w = 128; w > 0; w >>= 1){ if (tid < w) red[tid] += red[tid+w]; __syncthreads(); }
  if (tid == 0) pinv[p] = 1.0f / fmaxf(sqrtf(red[0]), 1e-8f);
}

// ---------------- prep: layer-0 qkv table [25][10][192] ----------------
__global__ void kTbl(const float* __restrict__ pos, const float* __restrict__ cemb,
                     const float* __restrict__ Wqkv, const float* __restrict__ bqkv,
                     float* __restrict__ tbl){
  __shared__ float e[64];
  int sc = blockIdx.x;            // s*10 + c
  int s = sc / 10, c = sc - s*10;
  int j = threadIdx.x;            // 0..191
  if (j < 64) e[j] = cemb[c*64 + j] + pos[s*64 + j];
  __syncthreads();
  const float* w = Wqkv + (size_t)j*64;   // layer 0 rows
  float a0=0.f,a1=0.f,a2=0.f,a3=0.f;
  #pragma unroll
  for (int d=0; d<64; d+=4){
    a0 = fmaf(e[d  ], w[d  ], a0);
    a1 = fmaf(e[d+1], w[d+1], a1);
    a2 = fmaf(e[d+2], w[d+2], a2);
    a3 = fmaf(e[d+3], w[d+3], a3);
  }
  tbl[(size_t)sc*192 + j] = ((a0+a1)+(a2+a3)) + bqkv[j];
}

// ---------------- main transformer: 1 block = 10 items, lane = row ----------------
__global__ __launch_bounds__(256,2) void kT(
  const float* __restrict__ gridin, const float* __restrict__ cemb, const float* __restrict__ pos,
  const float* __restrict__ Wqkv, const float* __restrict__ bqkv,
  const float* __restrict__ Wo,   const float* __restrict__ bo,
  const float* __restrict__ g1,   const float* __restrict__ be1,
  const float* __restrict__ W1,   const float* __restrict__ b1,
  const float* __restrict__ W2,   const float* __restrict__ b2,
  const float* __restrict__ g2,   const float* __restrict__ be2,
  const float* __restrict__ tbl,  float* __restrict__ xws, float* __restrict__ xinv, int B)
{
  __shared__ float smem[16800];
  float* kl   = smem;           // [250][16]
  float* vlds = smem + 4000;    // [250][16]
  float* ql   = smem + 8000;    // [250][16]
  float* tls  = smem;           // [250][66] (alias, phase-separated)
  float* fls  = smem;           // [250][18] (alias, phase-separated)
  float* red  = smem + 16500;   // [256]

  const int tid = threadIdx.x;
  const int r = tid;
  const int i = r / 25;
  const int s = r - i*25;
  const int gi = blockIdx.x * IPB + i;
  const bool act = (r < 250) && (gi < B);

  int am = 0;
  float x[64];
  if (act){
    const float* gp = gridin + (size_t)gi*250 + s;
    float mx = gp[0];
    #pragma unroll
    for (int c=1;c<10;c++){ float v = gp[c*25]; if (v > mx){ mx = v; am = c; } }
    const float4* ce = (const float4*)(cemb + am*64);
    const float4* pe = (const float4*)(pos  + s*64);
    #pragma unroll
    for (int u=0;u<16;u++){
      float4 a = ce[u], bb = pe[u];
      x[4*u+0]=a.x+bb.x; x[4*u+1]=a.y+bb.y; x[4*u+2]=a.z+bb.z; x[4*u+3]=a.w+bb.w;
    }
  }

  for (int l=0; l<2; l++){
    __syncthreads();   // protect kl/vl/ql region from previous phase (FFN fls alias)
    float o[64];
    #pragma unroll
    for (int d=0;d<64;d++) o[d]=0.f;

    #pragma unroll
    for (int h=0; h<4; h++){
      float q[16];
      if (act){
        if (l == 0){
          const float* tr = tbl + (size_t)(s*10+am)*192 + h*16;
          #pragma unroll
          for (int u=0;u<4;u++){
            float4 a = ((const float4*)tr)[u];
            q[4*u]=a.x; q[4*u+1]=a.y; q[4*u+2]=a.z; q[4*u+3]=a.w;
            ((float4*)(kl   + r*16))[u] = ((const float4*)(tr+64 ))[u];
            ((float4*)(vlds + r*16))[u] = ((const float4*)(tr+128))[u];
          }
        } else {
          #pragma unroll 1
          for (int jj=0;jj<16;jj++){
            const int row = h*16 + jj;
            const float* wq = Wqkv + (size_t)(192 + row)*64;
            const float* wk = Wqkv + (size_t)(192 + 64 + row)*64;
            const float* wv = Wqkv + (size_t)(192 + 128 + row)*64;
            ql[r*16+jj]   = dot64r(x, wq) + bqkv[192+row];
            kl[r*16+jj]   = dot64r(x, wk) + bqkv[192+64+row];
            vlds[r*16+jj] = dot64r(x, wv) + bqkv[192+128+row];
          }
        }
      }
      __syncthreads();
      if (act){
        if (l != 0){
          #pragma unroll
          for (int u=0;u<4;u++){
            float4 a = ((const float4*)(ql + r*16))[u];
            q[4*u]=a.x; q[4*u+1]=a.y; q[4*u+2]=a.z; q[4*u+3]=a.w;
          }
        }
        float att[25];
        float mx = -3.402823466e38f;
        #pragma unroll
        for (int kk=0;kk<25;kk++){
          const float4* kr = (const float4*)(kl + (i*25+kk)*16);
          float4 A=kr[0], Bq=kr[1], C=kr[2], D=kr[3];
          float p0 = q[0]*A.x,  p1 = q[1]*A.y,  p2 = q[2]*A.z,  p3 = q[3]*A.w;
          p0 = fmaf(q[4], Bq.x, p0); p1 = fmaf(q[5], Bq.y, p1); p2 = fmaf(q[6], Bq.z, p2); p3 = fmaf(q[7], Bq.w, p3);
          p0 = fmaf(q[8], C.x,  p0); p1 = fmaf(q[9], C.y,  p1); p2 = fmaf(q[10],C.z,  p2); p3 = fmaf(q[11],C.w,  p3);
          p0 = fmaf(q[12],D.x,  p0); p1 = fmaf(q[13],D.y,  p1); p2 = fmaf(q[14],D.z,  p2); p3 = fmaf(q[15],D.w,  p3);
          float v = ((p0+p1)+(p2+p3)) * 0.25f;
          att[kk] = v; mx = fmaxf(mx, v);
        }
        float ssum = 0.f;
        #pragma unroll
        for (int kk=0;kk<25;kk++){ float e = __expf(att[kk]-mx); att[kk]=e; ssum += e; }
        float rs = 1.0f / ssum;
        #pragma unroll
        for (int kk=0;kk<25;kk++){
          float a = att[kk]*rs;
          const float4* vr = (const float4*)(vlds + (i*25+kk)*16);
          float4 A=vr[0], Bq=vr[1], C=vr[2], D=vr[3];
          o[h*16+ 0]=fmaf(a,A.x ,o[h*16+ 0]); o[h*16+ 1]=fmaf(a,A.y ,o[h*16+ 1]);
          o[h*16+ 2]=fmaf(a,A.z ,o[h*16+ 2]); o[h*16+ 3]=fmaf(a,A.w ,o[h*16+ 3]);
          o[h*16+ 4]=fmaf(a,Bq.x,o[h*16+ 4]); o[h*16+ 5]=fmaf(a,Bq.y,o[h*16+ 5]);
          o[h*16+ 6]=fmaf(a,Bq.z,o[h*16+ 6]); o[h*16+ 7]=fmaf(a,Bq.w,o[h*16+ 7]);
          o[h*16+ 8]=fmaf(a,C.x ,o[h*16+ 8]); o[h*16+ 9]=fmaf(a,C.y ,o[h*16+ 9]);
          o[h*16+10]=fmaf(a,C.z ,o[h*16+10]); o[h*16+11]=fmaf(a,C.w ,o[h*16+11]);
          o[h*16+12]=fmaf(a,D.x ,o[h*16+12]); o[h*16+13]=fmaf(a,D.y ,o[h*16+13]);
          o[h*16+14]=fmaf(a,D.z ,o[h*16+14]); o[h*16+15]=fmaf(a,D.w ,o[h*16+15]);
        }
      }
      __syncthreads();
    }

    // o-projection + residual + LN1  (tls rows are per-lane private)
    if (act){
      #pragma unroll 1
      for (int j=0;j<64;j++){
        const float* wr = Wo + (size_t)(l*64 + j)*64;
        tls[r*66 + j] = dot64r(o, wr) + bo[l*64+j];
      }
      #pragma unroll
      for (int j=0;j<64;j+=2){
        float2 t = *(const float2*)(tls + r*66 + j);
        x[j] += t.x; x[j+1] += t.y;
      }
      ln64(x, g1 + l*64, be1 + l*64);
    }
    __syncthreads();   // tls reads done before fls (aliased region) writes

    if (act){
      float fa[64];
      #pragma unroll
      for (int j=0;j<64;j++) fa[j] = b2[l*64+j];
      #pragma unroll 1
      for (int t=0;t<8;t++){
        #pragma unroll 1
        for (int jj=0;jj<16;jj++){
          const float* wr = W1 + (size_t)(l*128 + t*16 + jj)*64;
          fls[r*18 + jj] = fmaxf(dot64r(x, wr) + b1[l*128 + t*16 + jj], 0.f);
        }
        float f1s[16];
        #pragma unroll
        for (int u=0;u<8;u++){
          float2 a = *(const float2*)(fls + r*18 + 2*u);
          f1s[2*u]=a.x; f1s[2*u+1]=a.y;
        }
        #pragma unroll
        for (int j=0;j<64;j++){
          const float* wr = W2 + (size_t)(l*64 + j)*128 + t*16;
          float a0 = f1s[0]*wr[0];
          float a1 = f1s[1]*wr[1];
          float a2 = f1s[2]*wr[2];
          float a3 = f1s[3]*wr[3];
          a0 = fmaf(f1s[ 4], wr[ 4], a0); a1 = fmaf(f1s[ 5], wr[ 5], a1);
          a2 = fmaf(f1s[ 6], wr[ 6], a2); a3 = fmaf(f1s[ 7], wr[ 7], a3);
          a0 = fmaf(f1s[ 8], wr[ 8], a0); a1 = fmaf(f1s[ 9], wr[ 9], a1);
          a2 = fmaf(f1s[10], wr[10], a2); a3 = fmaf(f1s[11], wr[11], a3);
          a0 = fmaf(f1s[12], wr[12], a0); a1 = fmaf(f1s[13], wr[13], a1);
          a2 = fmaf(f1s[14], wr[14], a2); a3 = fmaf(f1s[15], wr[15], a3);
          fa[j] += ((a0+a1)+(a2+a3));
        }
      }
      #pragma unroll
      for (int j=0;j<64;j++) x[j] += fa[j];
      ln64(x, g2 + l*64, be2 + l*64);
    }
  }

  // epilogue: write x, per-item inverse norm
  float ss = 0.f;
  if (act){
    float4* xo = (float4*)(xws + (size_t)(gi*25 + s)*64);
    float s0=0.f,s1=0.f,s2=0.f,s3=0.f;
    #pragma unroll
    for (int u=0;u<16;u++){
      float4 a; a.x=x[4*u]; a.y=x[4*u+1]; a.z=x[4*u+2]; a.w=x[4*u+3];
      xo[u] = a;
      s0=fmaf(a.x,a.x,s0); s1=fmaf(a.y,a.y,s1); s2=fmaf(a.z,a.z,s2); s3=fmaf(a.w,a.w,s3);
    }
    ss = (s0+s1)+(s2+s3);
  }
  red[tid] = ss;
  __syncthreads();
  if (tid < IPB){
    int g = blockIdx.x*IPB + tid;
    if (g < B){
      float t = 0.f;
      #pragma unroll
      for (int u=0;u<25;u++) t += red[tid*25+u];
      xinv[g] = 1.0f / fmaxf(sqrtf(t), 1e-8f);
    }
  }
}

// ---------------- scores GEMM: [B,1600] @ [1600,100]^T ----------------
__global__ __launch_bounds__(256,4) void kS(const float* __restrict__ xws, const float* __restrict__ xinv,
    const float* __restrict__ pm, const float* __restrict__ pinv, float* __restrict__ scr, int B){
  __shared__ float xt[64*36];
  __shared__ float pt[112*36];
  const int tid = threadIdx.x;
  const int pg = tid & 15, ig = tid >> 4;
  const int it0 = blockIdx.x * 64;
  float acc[4][7];
  #pragma unroll
  for (int a=0;a<4;a++)
    #pragma unroll
    for (int c=0;c<7;c++) acc[a][c] = 0.f;

  for (int k0 = 0; k0 < 1600; k0 += 32){
    __syncthreads();
    #pragma unroll
    for (int jj=0;jj<2;jj++){
      int cch = tid + jj*256;
      int row = cch >> 3, kc = cch & 7;
      int it = it0 + row; if (it >= B) it = B-1;
      *(float4*)(xt + row*36 + kc*4) = *(const float4*)(xws + (size_t)it*1600 + k0 + kc*4);
    }
    #pragma unroll
    for (int jj=0;jj<4;jj++){
      int cch = tid + jj*256;
      if (cch < 896){
        int row = cch >> 3, kc = cch & 7;
        float4 v;
        if (row < 100) v = *(const float4*)(pm + (size_t)row*1600 + k0 + kc*4);
        else { v.x=0.f; v.y=0.f; v.z=0.f; v.w=0.f; }
        *(float4*)(pt + row*36 + kc*4) = v;
      }
    }
    __syncthreads();
    #pragma unroll
    for (int k=0;k<32;k+=4){
      float4 xv[4], pv[7];
      #pragma unroll
      for (int a=0;a<4;a++) xv[a] = *(const float4*)(xt + (ig*4+a)*36 + k);
      #pragma unroll
      for (int c=0;c<7;c++) pv[c] = *(const float4*)(pt + (pg+16*c)*36 + k);
      #pragma unroll
      for (int a=0;a<4;a++)
        #pragma unroll
        for (int c=0;c<7;c++){
          float t = acc[a][c];
          t = fmaf(xv[a].x, pv[c].x, t);
          t = fmaf(xv[a].y, pv[c].y, t);
          t = fmaf(xv[a].z, pv[c].z, t);
          t = fmaf(xv[a].w, pv[c].w, t);
          acc[a][c] = t;
        }
    }
  }
  #pragma unroll
  for (int a=0;a<4;a++){
    int it = it0 + ig*4 + a;
    if (it < B){
      float xi = xinv[it];
      #pragma unroll
      for (int c=0;c<7;c++){
        int p = pg + 16*c;
        if (p < 100) scr[(size_t)it*100 + p] = acc[a][c] * xi * pinv[p];
      }
    }
  }
}

// ---------------- top-5 + influence + head + transposed store ----------------
__global__ __launch_bounds__(256,2) void kH(const float* __restrict__ xws, const float* __restrict__ scr,
   const float* __restrict__ pm, const float* __restrict__ hW1, const float* __restrict__ hb1,
   const float* __restrict__ hW2, const float* __restrict__ hb2, float* __restrict__ outp, int B){
  __shared__ float hls[16500];     // [250][66] per-lane private rows
  __shared__ int   tI[IPB*5];
  __shared__ float tW[IPB*5];
  const int tid = threadIdx.x;

  if (tid < IPB){
    int g = blockIdx.x*IPB + tid;
    if (g < B){
      const float* sc = scr + (size_t)g*100;
      float v0=-3.402823466e38f,v1=v0,v2=v0,v3=v0,v4=v0;
      int j0=0,j1=0,j2=0,j3=0,j4=0;
      for (int p=0;p<100;p++){
        float v = sc[p];
        if (v > v4){
          if (v > v2){
            if (v > v1){
              if (v > v0){ v4=v3;j4=j3; v3=v2;j3=j2; v2=v1;j2=j1; v1=v0;j1=j0; v0=v;j0=p; }
              else       { v4=v3;j4=j3; v3=v2;j3=j2; v2=v1;j2=j1; v1=v; j1=p; }
            } else       { v4=v3;j4=j3; v3=v2;j3=j2; v2=v; j2=p; }
          } else {
            if (v > v3)  { v4=v3;j4=j3; v3=v; j3=p; }
            else         { v4=v; j4=p; }
          }
        }
      }
      float e1=__expf(v1-v0), e2=__expf(v2-v0), e3=__expf(v3-v0), e4=__expf(v4-v0);
      float inv = 1.0f/(1.0f+e1+e2+e3+e4);
      tI[tid*5+0]=j0; tI[tid*5+1]=j1; tI[tid*5+2]=j2; tI[tid*5+3]=j3; tI[tid*5+4]=j4;
      tW[tid*5+0]=inv; tW[tid*5+1]=e1*inv; tW[tid*5+2]=e2*inv; tW[tid*5+3]=e3*inv; tW[tid*5+4]=e4*inv;
    }
  }
  __syncthreads();

  const int r = tid;
  const int i = r/25, s = r - i*25;
  const int gi = blockIdx.x*IPB + i;
  if (r < 250 && gi < B){
    float x[64];
    const float4* xi4 = (const float4*)(xws + (size_t)(gi*25+s)*64);
    #pragma unroll
    for (int u=0;u<16;u++){ float4 a = xi4[u]; x[4*u]=a.x; x[4*u+1]=a.y; x[4*u+2]=a.z; x[4*u+3]=a.w; }
    #pragma unroll
    for (int t=0;t<5;t++){
      float w = 0.5f * tW[i*5+t];
      const float4* pr = (const float4*)(pm + (size_t)tI[i*5+t]*1600 + s*64);
      #pragma unroll
      for (int u=0;u<16;u++){
        float4 a = pr[u];
        x[4*u  ]=fmaf(w,a.x,x[4*u  ]); x[4*u+1]=fmaf(w,a.y,x[4*u+1]);
        x[4*u+2]=fmaf(w,a.z,x[4*u+2]); x[4*u+3]=fmaf(w,a.w,x[4*u+3]);
      }
    }
    #pragma unroll 1
    for (int j=0;j<64;j++){
      hls[r*66+j] = fmaxf(dot64r(x, hW1 + (size_t)j*64) + hb1[j], 0.f);
    }
    float hreg[64];
    #pragma unroll
    for (int u=0;u<32;u++){ float2 a = *(const float2*)(hls + r*66 + 2*u); hreg[2*u]=a.x; hreg[2*u+1]=a.y; }
    #pragma unroll 1
    for (int c=0;c<10;c++){
      outp[(size_t)gi*250 + c*25 + s] = dot64r(hreg, hW2 + (size_t)c*64) + hb2[c];
    }
  }
}

extern "C" void kernel_launch(void* const* d_in, const int* in_sizes, int n_in,
                              void* d_out, int out_size, void* d_ws, size_t ws_size,
                              hipStream_t stream){
  (void)n_in; (void)out_size; (void)ws_size;
  const float* gridin = (const float*)d_in[0];
  const float* pos    = (const float*)d_in[1];
  const float* cemb   = (const float*)d_in[2];
  const float* Wqkv   = (const float*)d_in[3];
  const float* bqkv   = (const float*)d_in[4];
  const float* Wo     = (const float*)d_in[5];
  const float* bo     = (const float*)d_in[6];
  const float* g1     = (const float*)d_in[7];
  const float* be1    = (const float*)d_in[8];
  const float* W1     = (const float*)d_in[9];
  const float* b1     = (const float*)d_in[10];
  const float* W2     = (const float*)d_in[11];
  const float* b2     = (const float*)d_in[12];
  const float* g2     = (const float*)d_in[13];
  const float* be2    = (const float*)d_in[14];
  const float* pm     = (const float*)d_in[15];
  const float* hW1    = (const float*)d_in[16];
  const float* hb1    = (const float*)d_in[17];
  const float* hW2    = (const float*)d_in[18];
  const float* hb2    = (const float*)d_in[19];
  float* outp = (float*)d_out;
  const int B = in_sizes[0] / 250;

  float* ws    = (float*)d_ws;
  float* tbl   = ws;                         // 48000
  float* pinv  = ws + 48000;                 // 128 (100 used)
  float* xws   = ws + 48128;                 // B*1600
  float* xinv  = xws + (size_t)B*1600;       // B
  float* scr   = xinv + B;                   // B*100

  kPinv<<<100, 256, 0, stream>>>(pm, pinv);
  kTbl <<<250, 192, 0, stream>>>(pos, cemb, Wqkv, bqkv, tbl);
  kT   <<<(B + IPB - 1)/IPB, 256, 0, stream>>>(gridin, cemb, pos, Wqkv, bqkv, Wo, bo,
                                               g1, be1, W1, b1, W2, b2, g2, be2,
                                               tbl, xws, xinv, B);
  kS   <<<(B + 63)/64, 256, 0, stream>>>(xws, xinv, pm, pinv, scr, B);
  kH   <<<(B + IPB - 1)/IPB, 256, 0, stream>>>(xws, scr, pm, hW1, hb1, hW2, hb2, outp, B);
}